// Round 1
// 405.507 us; speedup vs baseline: 1.0326x; 1.0326x over previous
//
#include <hip/hip_runtime.h>
#include <hip/hip_bf16.h>

// Problem constants
#define NB 16      // batch
#define NN 1024    // nodes
#define CIN 16
#define TT 36
#define KK 3
#define COUT 64
#define CT 576     // CIN*TT
#define KB 48      // KK*NB

typedef __attribute__((ext_vector_type(8))) short bf16x8;
typedef __attribute__((ext_vector_type(4))) float f32x4;

__device__ __forceinline__ unsigned short f2bf(float f) {
    union { float f; unsigned int u; } v; v.f = f;
    unsigned int r = v.u + 0x7FFF + ((v.u >> 16) & 1);
    return (unsigned short)(r >> 16);
}

// -------- prep_a: At[l][n - n_base][m] = bf16(cheb[k][m][n] * SAt[b][m][n]) --------
// R1 rewrite: one block per (k, 64x64 tile position); loops b=0..15 with the cheb
// tile pinned in registers (cheb re-read 16x -> 1x) and one sat array streamed
// chip-wide per b-iteration. Grid = 768 = 3 blocks/CU, all co-resident; the three
// k-blocks of a position are ids x, x+256, x+512 (same XCD residue mod 8) so each
// sat tile lands in one XCD L2 and serves all 3 k's. Next-b sat load is issued
// before the barrier so it overlaps the transposed write-out.
__global__ __launch_bounds__(256) void prep_a(const float* __restrict__ cheb,
                                              const float* __restrict__ sat,
                                              ushort* __restrict__ At,
                                              int n_base, int rows) {
    __shared__ ushort tile[64][68];
    const int ntiles = rows >> 6;
    const int k = blockIdx.y;
    const int n0 = n_base + (blockIdx.x % ntiles) * 64;
    const int m0 = (blockIdx.x / ntiles) * 64;
    const int tid = threadIdx.x;

    size_t goff[4];
    float4 cv[4], sv[4];
#pragma unroll
    for (int i = 0; i < 4; ++i) {
        int f = i * 256 + tid;
        goff[i] = (size_t)(m0 + (f >> 4)) * NN + n0 + ((f & 15) << 2);
        cv[i] = *(const float4*)(cheb + (size_t)k * NN * NN + goff[i]);
        sv[i] = *(const float4*)(sat + goff[i]);      // b = 0
    }
    for (int b = 0; b < 16; ++b) {
#pragma unroll
        for (int i = 0; i < 4; ++i) {
            int f = i * 256 + tid;
            ushort4 u;
            u.x = f2bf(cv[i].x * sv[i].x); u.y = f2bf(cv[i].y * sv[i].y);
            u.z = f2bf(cv[i].z * sv[i].z); u.w = f2bf(cv[i].w * sv[i].w);
            *(ushort4*)&tile[f >> 4][(f & 15) << 2] = u;
        }
        if (b < 15) {
            const float* sa = sat + (size_t)(b + 1) * NN * NN;
#pragma unroll
            for (int i = 0; i < 4; ++i) sv[i] = *(const float4*)(sa + goff[i]);
        }
        __syncthreads();
        ushort* outp = At + (size_t)(k * 16 + b) * rows * NN;
#pragma unroll
        for (int i = 0; i < 4; ++i) {
            int f = i * 256 + tid;
            int n = f >> 4, m4 = (f & 15) << 2;
            ushort4 u;
            u.x = tile[m4 + 0][n]; u.y = tile[m4 + 1][n];
            u.z = tile[m4 + 2][n]; u.w = tile[m4 + 3][n];
            *(ushort4*)(outp + (size_t)(n0 - n_base + n) * NN + m0 + m4) = u;
        }
        __syncthreads();   // tile reused next b-iteration
    }
}

// -------- prep_x: Xt[b][ct'][m] = bf16(x[b][m][c][t]), ct' = t*16 + c --------
__global__ __launch_bounds__(256) void prep_x(const float* __restrict__ x,
                                              ushort* __restrict__ Xt) {
    __shared__ ushort tile[64][68];
    const int b = blockIdx.y;
    const int m0 = (blockIdx.x & 15) * 64;
    const int c0 = (blockIdx.x >> 4) * 64;
    const int tid = threadIdx.x;
    const float* xb = x + (size_t)b * NN * CT;
#pragma unroll
    for (int i = 0; i < 4; ++i) {
        int f = i * 256 + tid;
        int mr = f >> 4, c4 = (f & 15) << 2;
        float4 v = *(const float4*)(xb + (size_t)(m0 + mr) * CT + c0 + c4);
        ushort4 u;
        u.x = f2bf(v.x); u.y = f2bf(v.y); u.z = f2bf(v.z); u.w = f2bf(v.w);
        *(ushort4*)&tile[mr][c4] = u;
    }
    __syncthreads();
    ushort* outp = Xt + (size_t)b * CT * NN;
#pragma unroll
    for (int i = 0; i < 4; ++i) {
        int f = i * 256 + tid;
        int n = f >> 4, m4 = (f & 15) << 2;
        int ctlin = c0 + n;                     // = c*36 + t
        int c = ctlin / 36, t = ctlin - 36 * c;
        int ctp = t * 16 + c;                   // t-major permuted row
        ushort4 u;
        u.x = tile[m4 + 0][n]; u.y = tile[m4 + 1][n];
        u.z = tile[m4 + 2][n]; u.w = tile[m4 + 3][n];
        *(ushort4*)(outp + (size_t)ctp * NN + m0 + m4) = u;
    }
}

// -------- gemm1: rhs2[b][n][t][k*16+c] = sum_m At[n][m] * Xt[b][ct'][m] --------
// Tile BM=128(n) x BN=192(ct') x BK=64.
// XCD swizzle: flat id = x + 24*y, 24y % 8 == 0 -> XCD = x % 8 (round-robin model).
//   nt = x%8, ctt = x/8: the 3 blocks sharing an A-slice (same nt, ctt=0,1,2)
//   sit at x, x+8, x+16 -> same XCD -> A-slice served from that XCD's L2.
//   y: b = y/3, k = y%3 -> 3 consecutive y share Xt[b] (B chunks L2/L3-hot).
__global__ __launch_bounds__(256) void gemm1(const ushort* __restrict__ At,
                                             const ushort* __restrict__ Xt,
                                             ushort* __restrict__ rhs2,
                                             int nsplit, int n_base, int rows) {
    __shared__ ushort smem[128 * 200];            // 51.2 KB; lA/lB in first 40 KB
    ushort* lA = smem;                            // 128*64
    ushort* lB = smem + 128 * 64;                 // 192*64
    const int tid = threadIdx.x;
    const int y = blockIdx.y;
    const int b = y / 3, k = y - 3 * b;           // Xt-sharing trios adjacent
    const int l = k * 16 + b;                     // At chunk index (layout unchanged)
    const int ntiles = rows >> 7;                 // 128-row tiles in this chunk
    const int nt = blockIdx.x % ntiles;           // XCD-aligned A-slice id
    const int ctt = blockIdx.x / ntiles;          // 3 ct-tiles -> same XCD
    const int nloc0 = nt * 128;
    const int ct0 = ctt * 192;
    const ushort* Ab = At + ((size_t)l * (nsplit ? rows : NN) + nloc0) * NN;
    const ushort* Bb = Xt + (size_t)b * CT * NN + (size_t)ct0 * NN;
    const int w = tid >> 6, lane = tid & 63;
    const int wr = w >> 1, wc = w & 1;
    const int lrow = lane & 15, quad = lane >> 4;
    f32x4 acc[4][6] = {};

    for (int kt = 0; kt < 16; ++kt) {
        const int mk = kt * 64;
#pragma unroll
        for (int i = 0; i < 4; ++i) {
            int f = i * 256 + tid;
            int row = f >> 3, kk = (f & 7) << 3;
            __builtin_amdgcn_global_load_lds(
                (const __attribute__((address_space(1))) void*)(Ab + (size_t)row * NN + mk + kk),
                (__attribute__((address_space(3))) void*)(&lA[f * 8]), 16, 0, 0);
        }
#pragma unroll
        for (int i = 0; i < 6; ++i) {
            int f = i * 256 + tid;
            int row = f >> 3, kk = (f & 7) << 3;
            __builtin_amdgcn_global_load_lds(
                (const __attribute__((address_space(1))) void*)(Bb + (size_t)row * NN + mk + kk),
                (__attribute__((address_space(3))) void*)(&lB[f * 8]), 16, 0, 0);
        }
        __syncthreads();
#pragma unroll
        for (int kk0 = 0; kk0 < 64; kk0 += 32) {
            bf16x8 af[4], bfr[6];
#pragma unroll
            for (int mi = 0; mi < 4; ++mi)
                af[mi] = *(const bf16x8*)&lA[(wr * 64 + mi * 16 + lrow) * 64 + kk0 + quad * 8];
#pragma unroll
            for (int ni = 0; ni < 6; ++ni)
                bfr[ni] = *(const bf16x8*)&lB[(wc * 96 + ni * 16 + lrow) * 64 + kk0 + quad * 8];
#pragma unroll
            for (int mi = 0; mi < 4; ++mi)
#pragma unroll
                for (int ni = 0; ni < 6; ++ni)
                    acc[mi][ni] = __builtin_amdgcn_mfma_f32_16x16x32_bf16(
                        af[mi], bfr[ni], acc[mi][ni], 0, 0, 0);
        }
        __syncthreads();
    }

    // stage C (bf16) into LDS: row stride 200 breaks bank alignment
#pragma unroll
    for (int mi = 0; mi < 4; ++mi)
#pragma unroll
        for (int ni = 0; ni < 6; ++ni)
#pragma unroll
            for (int r = 0; r < 4; ++r)
                smem[(wr * 64 + mi * 16 + quad * 4 + r) * 200 + wc * 96 + ni * 16 + lrow] =
                    f2bf(acc[mi][ni][r]);
    __syncthreads();

    // cooperative store: 128 n x 12 t x 32B (16 c) segments into rhs2[b][n][t][48]
    for (int f = tid; f < 1536; f += 256) {
        int n = f / 12, tl = f - 12 * (f / 12);
        int t = ctt * 12 + tl;
        uint4 v0 = *(const uint4*)&smem[n * 200 + tl * 16];
        uint4 v1 = *(const uint4*)&smem[n * 200 + tl * 16 + 8];
        size_t g = (((size_t)b * NN + n_base + nloc0 + n) * 36 + t) * 48 + k * 16;
        *(uint4*)(rhs2 + g) = v0;
        *(uint4*)(rhs2 + g + 8) = v1;
    }
}

// -------- apply_mfma2: out[b,n,o,t] = relu(sum_kc rhs2[b,n,t,kc] * theta[kc,o]) --------
// 16 bn per block (4 per wave, sequential). Stores LDS-staged for 1KB bursts.
__global__ __launch_bounds__(256) void apply_mfma2(const ushort* __restrict__ rhs2,
                                                   const float* __restrict__ theta,
                                                   float* __restrict__ out) {
    __shared__ ushort thT[64 * 72];       // [o][kc], kc in [48,64) zeroed
    __shared__ float ostage[4][64 * 36];  // per-wave staging, 9216 B each
    const int tid = threadIdx.x;
    for (int f = tid; f < 64 * 64; f += 256) {
        int o = f >> 6, kc = f & 63;
        thT[o * 72 + kc] = f2bf((kc < 48) ? theta[kc * 64 + o] : 0.f);
    }
    __syncthreads();
    const int w = tid >> 6, lane = tid & 63;
    const int lrow = lane & 15, quad = lane >> 4;

    bf16x8 a[4][2];
#pragma unroll
    for (int mi = 0; mi < 4; ++mi)
#pragma unroll
        for (int kc = 0; kc < 2; ++kc)
            a[mi][kc] = *(const bf16x8*)&thT[(mi * 16 + lrow) * 72 + kc * 32 + quad * 8];

    float* ost = &ostage[w][0];
    for (int j = 0; j < 4; ++j) {
        const int bn = blockIdx.x * 16 + w * 4 + j;
        const ushort* rrow = rhs2 + (size_t)bn * (36 * 48);
        f32x4 acc[4][3] = {};
#pragma unroll
        for (int ni = 0; ni < 3; ++ni)
#pragma unroll
            for (int kc = 0; kc < 2; ++kc) {
                // t-col >= 36 and kc-pad read in-bounds garbage (rhs2 is first in
                // ws, Xt follows): masked by zero theta rows / t<36 staging guard.
                bf16x8 bf = *(const bf16x8*)(rrow + (ni * 16 + lrow) * 48 + kc * 32 + quad * 8);
#pragma unroll
                for (int mi = 0; mi < 4; ++mi)
                    acc[mi][ni] = __builtin_amdgcn_mfma_f32_16x16x32_bf16(
                        a[mi][kc], bf, acc[mi][ni], 0, 0, 0);
            }
#pragma unroll
        for (int mi = 0; mi < 4; ++mi)
#pragma unroll
            for (int ni = 0; ni < 3; ++ni)
#pragma unroll
                for (int r = 0; r < 4; ++r) {
                    int t = ni * 16 + lrow;
                    if (t < 36)
                        ost[(mi * 16 + quad * 4 + r) * 36 + t] = fmaxf(acc[mi][ni][r], 0.f);
                }
        // wave-local LDS write->read across lanes: drain lgkm explicitly
        asm volatile("s_waitcnt lgkmcnt(0)" ::: "memory");
        float* ob = out + (size_t)bn * (COUT * TT);
#pragma unroll
        for (int q = 0; q < 9; ++q) {
            int f = q * 64 + lane;            // 576 float4 per row
            *(float4*)&ob[f * 4] = *(const float4*)&ost[f * 4];
        }
    }
}

// -------- naive fallback: zero workspace, fully fused --------
__global__ __launch_bounds__(256) void naive_fused(const float* __restrict__ x,
                                                   const float* __restrict__ sat,
                                                   const float* __restrict__ cheb,
                                                   const float* __restrict__ theta,
                                                   float* __restrict__ out) {
    __shared__ float wgt[3][1024];
    __shared__ float rs[3][576];
    const int tid = threadIdx.x;
    const int n = blockIdx.x, b = blockIdx.y;
    for (int f = tid; f < 3 * 1024; f += 256) {
        int k = f >> 10, m = f & 1023;
        wgt[k][m] = cheb[(size_t)k * NN * NN + (size_t)m * NN + n] *
                    sat[(size_t)b * NN * NN + (size_t)m * NN + n];
    }
    __syncthreads();
    float a0[3] = {}, a1[3] = {}, a2[3] = {};
    const float* xb = x + (size_t)b * NN * CT;
    for (int m = 0; m < 1024; ++m) {
        const float* xr = xb + (size_t)m * CT;
        float x0 = xr[tid];
        float x1 = xr[256 + tid];
        float x2 = (tid < 64) ? xr[512 + tid] : 0.f;
#pragma unroll
        for (int k = 0; k < 3; ++k) {
            float wm = wgt[k][m];
            a0[k] += wm * x0; a1[k] += wm * x1; a2[k] += wm * x2;
        }
    }
#pragma unroll
    for (int k = 0; k < 3; ++k) {
        rs[k][tid] = a0[k];
        rs[k][256 + tid] = a1[k];
        if (tid < 64) rs[k][512 + tid] = a2[k];
    }
    __syncthreads();
    const int o = tid >> 2, tg = tid & 3;
    float oa[9] = {};
    for (int kc = 0; kc < 48; ++kc) {
        int k = kc >> 4, c = kc & 15;
        float th = theta[kc * 64 + o];
        const float* rp = &rs[k][c * TT + tg * 9];
#pragma unroll
        for (int j = 0; j < 9; ++j) oa[j] += th * rp[j];
    }
    float* ob = out + ((size_t)b * NN + n) * (COUT * TT);
#pragma unroll
    for (int j = 0; j < 9; ++j)
        ob[o * TT + tg * 9 + j] = fmaxf(oa[j], 0.f);
}

extern "C" void kernel_launch(void* const* d_in, const int* in_sizes, int n_in,
                              void* d_out, int out_size, void* d_ws, size_t ws_size,
                              hipStream_t stream) {
    const float* x     = (const float*)d_in[0];   // [B,N,CIN,T]
    const float* sat   = (const float*)d_in[1];   // [B,N,N]
    const float* cheb  = (const float*)d_in[2];   // [K,N,N]
    const float* theta = (const float*)d_in[3];   // [K,CIN,COUT]
    float* out = (float*)d_out;

    const size_t RHS2 = (size_t)NB * NN * 36 * 48;   // 28.3M ushorts (56.6 MB)
    const size_t XT   = (size_t)NB * CT * NN;        //  9.4M (18.9 MB)
    const size_t ATF  = (size_t)KB * NN * NN;        // 50.3M (100.7 MB) full At
    const size_t ATNS = (size_t)KB * 512 * NN;       // 25.2M (50.3 MB) n-half chunk
    const size_t needA     = (RHS2 + XT + ATF) * 2;  // 176,160,768 B
    const size_t needSplit = (RHS2 + XT + ATNS) * 2; // 125,829,120 B

    // layout: rhs2 FIRST (apply's bounded over-reads land in Xt), then Xt, At
    ushort* rhs2 = (ushort*)d_ws;
    ushort* Xt   = rhs2 + RHS2;
    ushort* At   = Xt + XT;

    if (ws_size >= needA) {
        prep_x<<<dim3(144, NB), 256, 0, stream>>>(x, Xt);
        prep_a<<<dim3(256, KK), 256, 0, stream>>>(cheb, sat, At, 0, 1024);
        gemm1<<<dim3(24, KB), 256, 0, stream>>>(At, Xt, rhs2, 0, 0, 1024);
        apply_mfma2<<<dim3(NB * NN / 16), 256, 0, stream>>>(rhs2, theta, out);
    } else if (ws_size >= needSplit) {
        prep_x<<<dim3(144, NB), 256, 0, stream>>>(x, Xt);
        for (int half = 0; half < 2; ++half) {
            int nb = half * 512;
            prep_a<<<dim3(128, KK), 256, 0, stream>>>(cheb, sat, At, nb, 512);
            gemm1<<<dim3(12, KB), 256, 0, stream>>>(At, Xt, rhs2, 1, nb, 512);
        }
        apply_mfma2<<<dim3(NB * NN / 16), 256, 0, stream>>>(rhs2, theta, out);
    } else {
        naive_fused<<<dim3(NN, NB), 256, 0, stream>>>(x, sat, cheb, theta, out);
    }
}

// Round 2
// 384.887 us; speedup vs baseline: 1.0880x; 1.0536x over previous
//
#include <hip/hip_runtime.h>
#include <hip/hip_bf16.h>

// Problem constants
#define NB 16      // batch
#define NN 1024    // nodes
#define CIN 16
#define TT 36
#define KK 3
#define COUT 64
#define CT 576     // CIN*TT
#define KB 48      // KK*NB

typedef __attribute__((ext_vector_type(8))) short bf16x8;
typedef __attribute__((ext_vector_type(4))) float f32x4;

__device__ __forceinline__ unsigned short f2bf(float f) {
    union { float f; unsigned int u; } v; v.f = f;
    unsigned int r = v.u + 0x7FFF + ((v.u >> 16) & 1);
    return (unsigned short)(r >> 16);
}

// -------- prep_a: At[l][n - n_base][m] = bf16(cheb[k][m][n] * SAt[b][m][n]) --------
// One block per (k, 64x64 tile position); loops b=0..15 with the cheb tile pinned
// in registers; next-b sat load issued before the barrier (overlaps write-out).
__global__ __launch_bounds__(256) void prep_a(const float* __restrict__ cheb,
                                              const float* __restrict__ sat,
                                              ushort* __restrict__ At,
                                              int n_base, int rows) {
    __shared__ ushort tile[64][68];
    const int ntiles = rows >> 6;
    const int k = blockIdx.y;
    const int n0 = n_base + (blockIdx.x % ntiles) * 64;
    const int m0 = (blockIdx.x / ntiles) * 64;
    const int tid = threadIdx.x;

    size_t goff[4];
    float4 cv[4], sv[4];
#pragma unroll
    for (int i = 0; i < 4; ++i) {
        int f = i * 256 + tid;
        goff[i] = (size_t)(m0 + (f >> 4)) * NN + n0 + ((f & 15) << 2);
        cv[i] = *(const float4*)(cheb + (size_t)k * NN * NN + goff[i]);
        sv[i] = *(const float4*)(sat + goff[i]);      // b = 0
    }
    for (int b = 0; b < 16; ++b) {
#pragma unroll
        for (int i = 0; i < 4; ++i) {
            int f = i * 256 + tid;
            ushort4 u;
            u.x = f2bf(cv[i].x * sv[i].x); u.y = f2bf(cv[i].y * sv[i].y);
            u.z = f2bf(cv[i].z * sv[i].z); u.w = f2bf(cv[i].w * sv[i].w);
            *(ushort4*)&tile[f >> 4][(f & 15) << 2] = u;
        }
        if (b < 15) {
            const float* sa = sat + (size_t)(b + 1) * NN * NN;
#pragma unroll
            for (int i = 0; i < 4; ++i) sv[i] = *(const float4*)(sa + goff[i]);
        }
        __syncthreads();
        ushort* outp = At + (size_t)(k * 16 + b) * rows * NN;
#pragma unroll
        for (int i = 0; i < 4; ++i) {
            int f = i * 256 + tid;
            int n = f >> 4, m4 = (f & 15) << 2;
            ushort4 u;
            u.x = tile[m4 + 0][n]; u.y = tile[m4 + 1][n];
            u.z = tile[m4 + 2][n]; u.w = tile[m4 + 3][n];
            *(ushort4*)(outp + (size_t)(n0 - n_base + n) * NN + m0 + m4) = u;
        }
        __syncthreads();   // tile reused next b-iteration
    }
}

// -------- prep_x: Xt[b][ct'][m] = bf16(x[b][m][c][t]), ct' = t*16 + c --------
__global__ __launch_bounds__(256) void prep_x(const float* __restrict__ x,
                                              ushort* __restrict__ Xt) {
    __shared__ ushort tile[64][68];
    const int b = blockIdx.y;
    const int m0 = (blockIdx.x & 15) * 64;
    const int c0 = (blockIdx.x >> 4) * 64;
    const int tid = threadIdx.x;
    const float* xb = x + (size_t)b * NN * CT;
#pragma unroll
    for (int i = 0; i < 4; ++i) {
        int f = i * 256 + tid;
        int mr = f >> 4, c4 = (f & 15) << 2;
        float4 v = *(const float4*)(xb + (size_t)(m0 + mr) * CT + c0 + c4);
        ushort4 u;
        u.x = f2bf(v.x); u.y = f2bf(v.y); u.z = f2bf(v.z); u.w = f2bf(v.w);
        *(ushort4*)&tile[mr][c4] = u;
    }
    __syncthreads();
    ushort* outp = Xt + (size_t)b * CT * NN;
#pragma unroll
    for (int i = 0; i < 4; ++i) {
        int f = i * 256 + tid;
        int n = f >> 4, m4 = (f & 15) << 2;
        int ctlin = c0 + n;                     // = c*36 + t
        int c = ctlin / 36, t = ctlin - 36 * c;
        int ctp = t * 16 + c;                   // t-major permuted row
        ushort4 u;
        u.x = tile[m4 + 0][n]; u.y = tile[m4 + 1][n];
        u.z = tile[m4 + 2][n]; u.w = tile[m4 + 3][n];
        *(ushort4*)(outp + (size_t)ctp * NN + m0 + m4) = u;
    }
}

// -------- gemm1: rhs2[b][n][t][k*16+c] = sum_m At[n][m] * Xt[b][ct'][m] --------
// R2: counted-vmcnt deep pipeline (T3/T4) + chunk-XOR LDS swizzle (T2) + setprio (T5).
// Tile BM=128(n) x BN=192(ct') x BK=64, 512 threads = 8 waves (2M x 4N),
// per-wave 64x48 = 4x3 16x16 frags. LDS: double-buffered A(128x64)+B(192x64) bf16
// = 81.9 KB -> 1 block/CU, 8 waves/CU (m201-template occupancy).
// Pipeline: 2 tiles in flight; after compute-barrier STAGE(kt+2) into freed buf,
// then s_waitcnt vmcnt(5)+s_barrier (kt+1's 5 loads drained, kt+2's 5 stay in
// flight -- never drain to 0 mid-loop). Raw s_barrier (no __syncthreads!) so the
// compiler can't insert the vmcnt(0) drain.
// Swizzle (rule #21, both-sides): LDS dest linear; global SOURCE pre-swizzled
// chunk c -> c ^ (row&7); ds_read uses chunk' = q ^ (row&7). row&7 == lrow&7 for
// all fragment rows (row = base + lrow, base % 8 == 0), so lanes 0-15 spread over
// 8 bank groups (2-way = free) instead of 16-way.
// XCD swizzle unchanged: grid.x=24 (8 nt x 3 ctt), XCD = x%8; A-slice sharers at
// x, x+8, x+16 -> same XCD L2.
__global__ __launch_bounds__(512) void gemm1(const ushort* __restrict__ At,
                                             const ushort* __restrict__ Xt,
                                             ushort* __restrict__ rhs2,
                                             int nsplit, int n_base, int rows) {
    __shared__ ushort lds[2 * 320 * 64];          // 81,920 B (two A+B buffers)
    const int tid = threadIdx.x;
    const int y = blockIdx.y;
    const int b = y / 3, k = y - 3 * b;           // Xt-sharing trios adjacent
    const int l = k * 16 + b;                     // At chunk index
    const int ntiles = rows >> 7;
    const int nt = blockIdx.x % ntiles;
    const int ctt = blockIdx.x / ntiles;
    const int nloc0 = nt * 128;
    const int ct0 = ctt * 192;
    const ushort* Ab = At + ((size_t)l * (nsplit ? rows : NN) + nloc0) * NN;
    const ushort* Bb = Xt + (size_t)b * CT * NN + (size_t)ct0 * NN;

    // staging geometry: slot s = (row = s>>3, chunk = s&7); 16B per slot.
    // source chunk pre-swizzled: c ^ (row&7)  (row&7 == srow&7 for +64k rows)
    const int srow = tid >> 3;                    // 0..63
    const int schunk = tid & 7;
    const int swz = schunk ^ (srow & 7);
    const ushort* a_src0 = Ab + (size_t)srow * NN + swz * 8;
    const ushort* b_src0 = Bb + (size_t)srow * NN + swz * 8;

    auto STAGE = [&](int kt, int p) {
        const int mk = kt * 64;
        ushort* base = lds + p * (320 * 64);
        const ushort* as = a_src0 + mk;
        const ushort* bs = b_src0 + mk;
#pragma unroll
        for (int i = 0; i < 2; ++i)               // A: 128 rows x 8 chunks
            __builtin_amdgcn_global_load_lds(
                (const __attribute__((address_space(1))) void*)(as + (size_t)i * 64 * NN),
                (__attribute__((address_space(3))) void*)(base + (tid + i * 512) * 8), 16, 0, 0);
#pragma unroll
        for (int i = 0; i < 3; ++i)               // B: 192 rows x 8 chunks
            __builtin_amdgcn_global_load_lds(
                (const __attribute__((address_space(1))) void*)(bs + (size_t)i * 64 * NN),
                (__attribute__((address_space(3))) void*)(base + 128 * 64 + (tid + i * 512) * 8), 16, 0, 0);
    };

    const int w = tid >> 6, lane = tid & 63;
    const int wr = w >> 2, wc = w & 3;            // 2 x 4 wave grid
    const int lrow = lane & 15, quad = lane >> 4;
    const int koff0 = ((quad ^ (lrow & 7)) << 3); // swizzled k-chunk, kk0=0
    f32x4 acc[4][3] = {};

    STAGE(0, 0);                                  //  5 in flight
    STAGE(1, 1);                                  // 10 in flight
    asm volatile("s_waitcnt vmcnt(5)\n\ts_barrier" ::: "memory");   // tile 0 ready

    for (int kt = 0; kt < 16; ++kt) {
        const int p = kt & 1;
        const ushort* bufA = lds + p * (320 * 64);
        const ushort* bufB = bufA + 128 * 64;
#pragma unroll
        for (int kp = 0; kp < 2; ++kp) {
            const int koff = koff0 ^ (kp << 5);   // chunk ^= 4 for kk0=32
            bf16x8 af[4], bfr[3];
#pragma unroll
            for (int mi = 0; mi < 4; ++mi)
                af[mi] = *(const bf16x8*)&bufA[(wr * 64 + mi * 16 + lrow) * 64 + koff];
#pragma unroll
            for (int ni = 0; ni < 3; ++ni)
                bfr[ni] = *(const bf16x8*)&bufB[(wc * 48 + ni * 16 + lrow) * 64 + koff];
            __builtin_amdgcn_s_setprio(1);
#pragma unroll
            for (int mi = 0; mi < 4; ++mi)
#pragma unroll
                for (int ni = 0; ni < 3; ++ni)
                    acc[mi][ni] = __builtin_amdgcn_mfma_f32_16x16x32_bf16(
                        af[mi], bfr[ni], acc[mi][ni], 0, 0, 0);
            __builtin_amdgcn_s_setprio(0);
        }
        asm volatile("s_barrier" ::: "memory");   // all waves done reading buf p
        if (kt + 2 < 16) {
            STAGE(kt + 2, p);                     // overwrite freed buf; 10 in flight
            // drain kt+1's 5 (oldest), keep kt+2's 5 in flight across the barrier
            asm volatile("s_waitcnt vmcnt(5)\n\ts_barrier" ::: "memory");
        } else if (kt + 1 < 16) {
            asm volatile("s_waitcnt vmcnt(0)\n\ts_barrier" ::: "memory");  // last tile
        }
    }

    // stage C (bf16) into LDS (reuse pipeline buffers; row stride 200 breaks banks)
    ushort* cs = lds;
#pragma unroll
    for (int mi = 0; mi < 4; ++mi)
#pragma unroll
        for (int ni = 0; ni < 3; ++ni)
#pragma unroll
            for (int r = 0; r < 4; ++r)
                cs[(wr * 64 + mi * 16 + quad * 4 + r) * 200 + wc * 48 + ni * 16 + lrow] =
                    f2bf(acc[mi][ni][r]);
    __syncthreads();

    // cooperative store: 128 n x 12 t x 32B (16 c) segments into rhs2[b][n][t][48]
    for (int f = tid; f < 1536; f += 512) {
        int n = f / 12, tl = f - 12 * (f / 12);
        int t = ctt * 12 + tl;
        uint4 v0 = *(const uint4*)&cs[n * 200 + tl * 16];
        uint4 v1 = *(const uint4*)&cs[n * 200 + tl * 16 + 8];
        size_t g = (((size_t)b * NN + n_base + nloc0 + n) * 36 + t) * 48 + k * 16;
        *(uint4*)(rhs2 + g) = v0;
        *(uint4*)(rhs2 + g + 8) = v1;
    }
}

// -------- apply_mfma2: out[b,n,o,t] = relu(sum_kc rhs2[b,n,t,kc] * theta[kc,o]) --------
// 16 bn per block (4 per wave, sequential). Stores LDS-staged for 1KB bursts.
__global__ __launch_bounds__(256) void apply_mfma2(const ushort* __restrict__ rhs2,
                                                   const float* __restrict__ theta,
                                                   float* __restrict__ out) {
    __shared__ ushort thT[64 * 72];       // [o][kc], kc in [48,64) zeroed
    __shared__ float ostage[4][64 * 36];  // per-wave staging, 9216 B each
    const int tid = threadIdx.x;
    for (int f = tid; f < 64 * 64; f += 256) {
        int o = f >> 6, kc = f & 63;
        thT[o * 72 + kc] = f2bf((kc < 48) ? theta[kc * 64 + o] : 0.f);
    }
    __syncthreads();
    const int w = tid >> 6, lane = tid & 63;
    const int lrow = lane & 15, quad = lane >> 4;

    bf16x8 a[4][2];
#pragma unroll
    for (int mi = 0; mi < 4; ++mi)
#pragma unroll
        for (int kc = 0; kc < 2; ++kc)
            a[mi][kc] = *(const bf16x8*)&thT[(mi * 16 + lrow) * 72 + kc * 32 + quad * 8];

    float* ost = &ostage[w][0];
    for (int j = 0; j < 4; ++j) {
        const int bn = blockIdx.x * 16 + w * 4 + j;
        const ushort* rrow = rhs2 + (size_t)bn * (36 * 48);
        f32x4 acc[4][3] = {};
#pragma unroll
        for (int ni = 0; ni < 3; ++ni)
#pragma unroll
            for (int kc = 0; kc < 2; ++kc) {
                // t-col >= 36 and kc-pad read in-bounds garbage (rhs2 is first in
                // ws, Xt follows): masked by zero theta rows / t<36 staging guard.
                bf16x8 bf = *(const bf16x8*)(rrow + (ni * 16 + lrow) * 48 + kc * 32 + quad * 8);
#pragma unroll
                for (int mi = 0; mi < 4; ++mi)
                    acc[mi][ni] = __builtin_amdgcn_mfma_f32_16x16x32_bf16(
                        a[mi][kc], bf, acc[mi][ni], 0, 0, 0);
            }
#pragma unroll
        for (int mi = 0; mi < 4; ++mi)
#pragma unroll
            for (int ni = 0; ni < 3; ++ni)
#pragma unroll
                for (int r = 0; r < 4; ++r) {
                    int t = ni * 16 + lrow;
                    if (t < 36)
                        ost[(mi * 16 + quad * 4 + r) * 36 + t] = fmaxf(acc[mi][ni][r], 0.f);
                }
        // wave-local LDS write->read across lanes: drain lgkm explicitly
        asm volatile("s_waitcnt lgkmcnt(0)" ::: "memory");
        float* ob = out + (size_t)bn * (COUT * TT);
#pragma unroll
        for (int q = 0; q < 9; ++q) {
            int f = q * 64 + lane;            // 576 float4 per row
            *(float4*)&ob[f * 4] = *(const float4*)&ost[f * 4];
        }
    }
}

// -------- naive fallback: zero workspace, fully fused --------
__global__ __launch_bounds__(256) void naive_fused(const float* __restrict__ x,
                                                   const float* __restrict__ sat,
                                                   const float* __restrict__ cheb,
                                                   const float* __restrict__ theta,
                                                   float* __restrict__ out) {
    __shared__ float wgt[3][1024];
    __shared__ float rs[3][576];
    const int tid = threadIdx.x;
    const int n = blockIdx.x, b = blockIdx.y;
    for (int f = tid; f < 3 * 1024; f += 256) {
        int k = f >> 10, m = f & 1023;
        wgt[k][m] = cheb[(size_t)k * NN * NN + (size_t)m * NN + n] *
                    sat[(size_t)b * NN * NN + (size_t)m * NN + n];
    }
    __syncthreads();
    float a0[3] = {}, a1[3] = {}, a2[3] = {};
    const float* xb = x + (size_t)b * NN * CT;
    for (int m = 0; m < 1024; ++m) {
        const float* xr = xb + (size_t)m * CT;
        float x0 = xr[tid];
        float x1 = xr[256 + tid];
        float x2 = (tid < 64) ? xr[512 + tid] : 0.f;
#pragma unroll
        for (int k = 0; k < 3; ++k) {
            float wm = wgt[k][m];
            a0[k] += wm * x0; a1[k] += wm * x1; a2[k] += wm * x2;
        }
    }
#pragma unroll
    for (int k = 0; k < 3; ++k) {
        rs[k][tid] = a0[k];
        rs[k][256 + tid] = a1[k];
        if (tid < 64) rs[k][512 + tid] = a2[k];
    }
    __syncthreads();
    const int o = tid >> 2, tg = tid & 3;
    float oa[9] = {};
    for (int kc = 0; kc < 48; ++kc) {
        int k = kc >> 4, c = kc & 15;
        float th = theta[kc * 64 + o];
        const float* rp = &rs[k][c * TT + tg * 9];
#pragma unroll
        for (int j = 0; j < 9; ++j) oa[j] += th * rp[j];
    }
    float* ob = out + ((size_t)b * NN + n) * (COUT * TT);
#pragma unroll
    for (int j = 0; j < 9; ++j)
        ob[o * TT + tg * 9 + j] = fmaxf(oa[j], 0.f);
}

extern "C" void kernel_launch(void* const* d_in, const int* in_sizes, int n_in,
                              void* d_out, int out_size, void* d_ws, size_t ws_size,
                              hipStream_t stream) {
    const float* x     = (const float*)d_in[0];   // [B,N,CIN,T]
    const float* sat   = (const float*)d_in[1];   // [B,N,N]
    const float* cheb  = (const float*)d_in[2];   // [K,N,N]
    const float* theta = (const float*)d_in[3];   // [K,CIN,COUT]
    float* out = (float*)d_out;

    const size_t RHS2 = (size_t)NB * NN * 36 * 48;   // 28.3M ushorts (56.6 MB)
    const size_t XT   = (size_t)NB * CT * NN;        //  9.4M (18.9 MB)
    const size_t ATF  = (size_t)KB * NN * NN;        // 50.3M (100.7 MB) full At
    const size_t ATNS = (size_t)KB * 512 * NN;       // 25.2M (50.3 MB) n-half chunk
    const size_t needA     = (RHS2 + XT + ATF) * 2;  // 176,160,768 B
    const size_t needSplit = (RHS2 + XT + ATNS) * 2; // 125,829,120 B

    // layout: rhs2 FIRST (apply's bounded over-reads land in Xt), then Xt, At
    ushort* rhs2 = (ushort*)d_ws;
    ushort* Xt   = rhs2 + RHS2;
    ushort* At   = Xt + XT;

    if (ws_size >= needA) {
        prep_x<<<dim3(144, NB), 256, 0, stream>>>(x, Xt);
        prep_a<<<dim3(256, KK), 256, 0, stream>>>(cheb, sat, At, 0, 1024);
        gemm1<<<dim3(24, KB), 512, 0, stream>>>(At, Xt, rhs2, 0, 0, 1024);
        apply_mfma2<<<dim3(NB * NN / 16), 256, 0, stream>>>(rhs2, theta, out);
    } else if (ws_size >= needSplit) {
        prep_x<<<dim3(144, NB), 256, 0, stream>>>(x, Xt);
        for (int half = 0; half < 2; ++half) {
            int nb = half * 512;
            prep_a<<<dim3(128, KK), 256, 0, stream>>>(cheb, sat, At, nb, 512);
            gemm1<<<dim3(12, KB), 512, 0, stream>>>(At, Xt, rhs2, 1, nb, 512);
        }
        apply_mfma2<<<dim3(NB * NN / 16), 256, 0, stream>>>(rhs2, theta, out);
    } else {
        naive_fused<<<dim3(NN, NB), 256, 0, stream>>>(x, sat, cheb, theta, out);
    }
}